// Round 8
// baseline (349.758 us; speedup 1.0000x reference)
//
#include <hip/hip_runtime.h>

// GAT_gate: B=8, N=2048, D=128
// out = c*x + (1-c)*relu(att@h), att = colsoftmax(mask(hA h^T + h hA^T))*adj
// e small (|e|<~6) -> exp without max-subtraction (clamp 60).
// cat[n][0:128]=hA[n], cat[n][128:256]=h[n]; e[i,j] = cat[i] . catsw[j].
// R8 = bisect: R7 (R4-proven k1/k1v + k2' no-LDS + k3' K-split) failed at 221
// ~ unnormalized-row magnitude -> k3' prime suspect (k2' is element-identical
// to R4's passing k2). This round: KEEP k2' (no-LDS/no-barrier), RESTORE R4's
// exact passing k3 (LDS-staged, block 256). Pass -> k3' guilty + bank k2 win.

#define B_ 8
#define N_ 2048
#define D_ 128

typedef __attribute__((ext_vector_type(8))) short short8;
typedef __attribute__((ext_vector_type(4))) float f32x4;

#define GLL(gp, lp) __builtin_amdgcn_global_load_lds( \
    (__attribute__((address_space(1))) const unsigned int*)(gp), \
    (__attribute__((address_space(3))) unsigned int*)(lp), 16, 0, 0)

static __device__ __forceinline__ unsigned short f2bf(float f) {
  union { float f; unsigned int u; } v; v.f = f;
  unsigned int r = v.u + 0x7fffu + ((v.u >> 16) & 1u);
  return (unsigned short)(r >> 16);
}
static __device__ __forceinline__ float bf2f(unsigned short u) {
  union { unsigned int u; float f; } v; v.u = ((unsigned int)u) << 16;
  return v.f;
}

// ---- workspace layout (bytes) ----
#define CAT_OFF ((size_t)0)         // bf16 cat [B][N][256]        8 MB
#define VT_OFF  ((size_t)8388608)   // bf16 V'^T [B][128][N]       4 MB
#define PUN_OFF ((size_t)12582912)  // bf16 P_un [B][N][N]         67.1 MB
#define S_OFF   ((size_t)79691776)  // f32 colsum s [B][N]         64 KB
#define WT_OFF  ((size_t)79757312)  // f32 W^T [128][128]          64 KB

// ---------- prep: W transpose (R4-proven) ----------
__global__ void k_wt(const float* __restrict__ W, float* __restrict__ Wt) {
  int t = threadIdx.x;
  for (int i = t; i < 128 * 128; i += 256) {
    int d = i >> 7, f = i & 127;
    Wt[f * 128 + d] = W[i];
  }
}

// ---------- k1: h = xW^T + b, hA = h@A in fp32 ; write cat bf16 (R4-proven) ----------
__global__ __launch_bounds__(256) void k1(const float* __restrict__ x,
                                          const float* __restrict__ Wt,
                                          const float* __restrict__ Wb,
                                          const float* __restrict__ A,
                                          unsigned short* __restrict__ cat) {
  __shared__ float xs[8][128];
  __shared__ float hs[8][128];
  const int t = threadIdx.x;
  const size_t rowbase = (size_t)blockIdx.x * 8;
  {
    int row = t >> 5, part = t & 31;
    *(f32x4*)&xs[row][part * 4] = *(const f32x4*)(x + (rowbase + row) * D_ + part * 4);
  }
  __syncthreads();
  const int d = t & 127, r2 = t >> 7;
  float a0 = 0, a1 = 0, a2 = 0, a3 = 0;
  for (int f = 0; f < 128; f++) {
    float wv = Wt[f * 128 + d];
    a0 += xs[r2 * 4 + 0][f] * wv;
    a1 += xs[r2 * 4 + 1][f] * wv;
    a2 += xs[r2 * 4 + 2][f] * wv;
    a3 += xs[r2 * 4 + 3][f] * wv;
  }
  float wb = Wb[d];
  a0 += wb; a1 += wb; a2 += wb; a3 += wb;
  hs[r2 * 4 + 0][d] = a0; hs[r2 * 4 + 1][d] = a1;
  hs[r2 * 4 + 2][d] = a2; hs[r2 * 4 + 3][d] = a3;
  cat[(rowbase + r2 * 4 + 0) * 256 + 128 + d] = f2bf(a0);
  cat[(rowbase + r2 * 4 + 1) * 256 + 128 + d] = f2bf(a1);
  cat[(rowbase + r2 * 4 + 2) * 256 + 128 + d] = f2bf(a2);
  cat[(rowbase + r2 * 4 + 3) * 256 + 128 + d] = f2bf(a3);
  __syncthreads();
  float b0 = 0, b1 = 0, b2 = 0, b3 = 0;
  for (int f = 0; f < 128; f++) {
    float av = A[f * 128 + d];
    b0 += hs[r2 * 4 + 0][f] * av;
    b1 += hs[r2 * 4 + 1][f] * av;
    b2 += hs[r2 * 4 + 2][f] * av;
    b3 += hs[r2 * 4 + 3][f] * av;
  }
  cat[(rowbase + r2 * 4 + 0) * 256 + d] = f2bf(b0);
  cat[(rowbase + r2 * 4 + 1) * 256 + d] = f2bf(b1);
  cat[(rowbase + r2 * 4 + 2) * 256 + d] = f2bf(b2);
  cat[(rowbase + r2 * 4 + 3) * 256 + d] = f2bf(b3);
}

// ---------- k2: E once; s[k] += adj*exp(E); P_un packed-pair bf16 ----------
// grid (16, 16, 8); 4 waves; NO LDS, NO BARRIERS. Wave w owns k-cols
// (blockIdx.x*4+w)*32 .. +32 (lane pair 2*l15, 2*l15+1), j-span 128.
__global__ __launch_bounds__(256) void k2(const unsigned short* __restrict__ cat,
                                          const float* __restrict__ adj,
                                          unsigned short* __restrict__ pun,
                                          float* __restrict__ s_out) {
  const int t = threadIdx.x, w = t >> 6, lane = t & 63;
  const int q = lane >> 4, l15 = lane & 15;
  const int b = blockIdx.z;
  const int kc = (blockIdx.x * 4 + w) * 32;
  const int j0 = blockIdx.y * 128;
  const size_t bN = (size_t)b * N_;
  const unsigned short* catp = cat + (bN << 8);
  short8 brg[2][8];  // catsw_k fragments (swap = +16 chunks mod 32)
#pragma unroll
  for (int p = 0; p < 2; p++)
#pragma unroll
    for (int m = 0; m < 8; m++)
      brg[p][m] = *(const short8*)(catp + (((size_t)(kc + 2 * l15 + p)) << 8) +
                                   ((((m * 4 + q) + 16) & 31) * 8));
  float acc0 = 0.f, acc1 = 0.f;
  float2 av[4];
#pragma unroll
  for (int r = 0; r < 4; r++)
    av[r] = *(const float2*)(adj + ((bN + j0 + q * 4 + r) << 11) + kc + 2 * l15);
#pragma unroll 2
  for (int jsub = 0; jsub < 8; jsub++) {
    const int jr = j0 + jsub * 16;
    short8 afr[8];
#pragma unroll
    for (int m = 0; m < 8; m++)
      afr[m] = *(const short8*)(catp + (((size_t)(jr + l15)) << 8) + (m * 4 + q) * 8);
    f32x4 e0 = {0.f, 0.f, 0.f, 0.f}, e1 = {0.f, 0.f, 0.f, 0.f};
#pragma unroll
    for (int m = 0; m < 8; m++) {
      e0 = __builtin_amdgcn_mfma_f32_16x16x32_bf16(afr[m], brg[0][m], e0, 0, 0, 0);
      e1 = __builtin_amdgcn_mfma_f32_16x16x32_bf16(afr[m], brg[1][m], e1, 0, 0, 0);
    }
    float2 avc[4];
#pragma unroll
    for (int r = 0; r < 4; r++) avc[r] = av[r];
    if (jsub < 7) {
#pragma unroll
      for (int r = 0; r < 4; r++)
        av[r] = *(const float2*)(adj + ((bN + jr + 16 + q * 4 + r) << 11) + kc + 2 * l15);
    }
#pragma unroll
    for (int r = 0; r < 4; r++) {
      float x0 = avc[r].x > 0.f ? __expf(fminf(e0[r], 60.f)) : 0.f;
      float x1 = avc[r].y > 0.f ? __expf(fminf(e1[r], 60.f)) : 0.f;
      acc0 += x0; acc1 += x1;
      unsigned int pk = (unsigned int)f2bf(x0) | ((unsigned int)f2bf(x1) << 16);
      *(unsigned int*)(pun + ((bN + jr + q * 4 + r) << 11) + kc + 2 * l15) = pk;
    }
  }
  acc0 += __shfl_xor(acc0, 16, 64); acc0 += __shfl_xor(acc0, 32, 64);
  acc1 += __shfl_xor(acc1, 16, 64); acc1 += __shfl_xor(acc1, 32, 64);
  if (lane < 16) {
    atomicAdd(&s_out[bN + kc + 2 * lane], acc0);
    atomicAdd(&s_out[bN + kc + 2 * lane + 1], acc1);
  }
}

// ---------- k1v: vt[b][d][j] = bf16(h[b][j][d] / s[j]) (R4-proven) ----------
__global__ __launch_bounds__(256) void k1v(const unsigned short* __restrict__ cat,
                                           const float* __restrict__ s,
                                           unsigned short* __restrict__ vt) {
  __shared__ unsigned short tile[64][136];
  __shared__ float rsv[64];
  const int t = threadIdx.x;
  const int b = blockIdx.y;
  const int nbase = blockIdx.x * 64;
  if (t < 64) rsv[t] = 1.f / s[(size_t)b * N_ + nbase + t];
#pragma unroll
  for (int k = 0; k < 4; k++) {
    int sI = t + 256 * k;
    int row = sI >> 4, part = sI & 15;
    *(short8*)&tile[row][part * 8] =
        *(const short8*)(cat + (((size_t)(b * N_ + nbase + row)) << 8) + 128 + part * 8);
  }
  __syncthreads();
#pragma unroll
  for (int k = 0; k < 4; k++) {
    int sI = t + 256 * k;
    int dd = sI >> 3, part = sI & 7;
    unsigned short tmp[8];
#pragma unroll
    for (int j = 0; j < 8; j++) {
      int jj = part * 8 + j;
      tmp[j] = f2bf(bf2f(tile[jj][dd]) * rsv[jj]);
    }
    *(short8*)(vt + (((size_t)(b * 128 + dd)) << 11) + nbase + part * 8) = *(short8*)tmp;
  }
}

// ---------- k3: h' = P_un @ V'; out = c*x + (1-c)*relu(h') (R4-proven) ----------
// grid (N/32, B); 4 waves; wave w owns d-group [w*32, w*32+32); j-tile 128.
__global__ __launch_bounds__(256) void k3(const unsigned short* __restrict__ pun,
                                          const unsigned short* __restrict__ vt,
                                          const float* __restrict__ x,
                                          const float* __restrict__ gw,
                                          const float* __restrict__ gb,
                                          float* __restrict__ out) {
  __shared__ char smem[40960];
  // [0,8192): A-tile P_un 32 x 128j   [8192,40960): B-tile vt 128d x 128j
  const int t = threadIdx.x, w = t >> 6, lane = t & 63;
  const int q = lane >> 4, l15 = lane & 15;
  const int b = blockIdx.y, i0 = blockIdx.x * 32;
  const size_t bN = (size_t)b * N_;
  unsigned short* pa = (unsigned short*)smem;
  unsigned short* vb = (unsigned short*)(smem + 8192);

  f32x4 acc[2][2];
#pragma unroll
  for (int ih = 0; ih < 2; ih++)
#pragma unroll
    for (int dh = 0; dh < 2; dh++) acc[ih][dh] = (f32x4){0.f, 0.f, 0.f, 0.f};

  for (int jt = 0; jt < N_ / 128; jt++) {
    const int j0 = jt * 128;
#pragma unroll
    for (int it = 0; it < 10; it++) {
      int sI = it * 256 + t;
      const unsigned short* g;
      if (sI < 512) {
        int row = sI >> 4, c = sI & 15;
        g = pun + (((size_t)(bN + i0 + row)) << 11) + j0 + ((c ^ (row & 7)) * 8);
      } else {
        int s2 = sI - 512;
        int dd = s2 >> 4, c = s2 & 15;
        g = vt + (((size_t)(b * 128 + dd)) << 11) + j0 + ((c ^ (dd & 7)) * 8);
      }
      GLL(g, smem + sI * 16);
    }
    __syncthreads();
#pragma unroll
    for (int ks = 0; ks < 4; ks++) {
      short8 af[2], bf[2];
#pragma unroll
      for (int ih = 0; ih < 2; ih++) {
        int m = ih * 16 + l15;
        af[ih] = *(short8*)(pa + m * 128 + (((ks * 4 + q) ^ (m & 7)) * 8));
      }
#pragma unroll
      for (int dh = 0; dh < 2; dh++) {
        int d = w * 32 + dh * 16 + l15;
        bf[dh] = *(short8*)(vb + d * 128 + (((ks * 4 + q) ^ (d & 7)) * 8));
      }
      acc[0][0] = __builtin_amdgcn_mfma_f32_16x16x32_bf16(af[0], bf[0], acc[0][0], 0, 0, 0);
      acc[0][1] = __builtin_amdgcn_mfma_f32_16x16x32_bf16(af[0], bf[1], acc[0][1], 0, 0, 0);
      acc[1][0] = __builtin_amdgcn_mfma_f32_16x16x32_bf16(af[1], bf[0], acc[1][0], 0, 0, 0);
      acc[1][1] = __builtin_amdgcn_mfma_f32_16x16x32_bf16(af[1], bf[1], acc[1][1], 0, 0, 0);
    }
    __syncthreads();
  }
  // epilogue: relu -> LDS f32, gate, sigmoid, blend, store
  float* hs = (float*)smem;            // 32 x 132 f32 = 16896 B
  float* co = (float*)(smem + 16896);  // 32 f32
#pragma unroll
  for (int ih = 0; ih < 2; ih++)
#pragma unroll
    for (int dh = 0; dh < 2; dh++)
#pragma unroll
      for (int r = 0; r < 4; r++) {
        int row = ih * 16 + q * 4 + r;
        int d = w * 32 + dh * 16 + l15;
        hs[row * 132 + d] = fmaxf(acc[ih][dh][r], 0.f);
      }
  __syncthreads();
  {
    int grow = t >> 3, sub = t & 7;
    const float* xr = x + (((size_t)(bN + i0 + grow)) << 7);
    float z = 0.f;
#pragma unroll
    for (int k = 0; k < 16; k++) {
      int dd = sub + 8 * k;
      z += gw[dd] * xr[dd] + gw[128 + dd] * hs[grow * 132 + dd];
    }
    z += __shfl_xor(z, 1, 64);
    z += __shfl_xor(z, 2, 64);
    z += __shfl_xor(z, 4, 64);
    if (sub == 0) co[grow] = 1.f / (1.f + __expf(-(z + gb[0])));
  }
  __syncthreads();
#pragma unroll
  for (int kk = 0; kk < 4; kk++) {
    int id = kk * 256 + t;
    int row = id >> 5, c4 = id & 31;
    size_t g = (((size_t)(bN + i0 + row)) << 7) + c4 * 4;
    f32x4 xv = *(const f32x4*)(x + g);
    f32x4 hv = *(const f32x4*)(hs + row * 132 + c4 * 4);
    float cf = co[row];
    f32x4 o;
#pragma unroll
    for (int e = 0; e < 4; e++) o[e] = cf * xv[e] + (1.f - cf) * hv[e];
    *(f32x4*)(out + g) = o;
  }
}

extern "C" void kernel_launch(void* const* d_in, const int* in_sizes, int n_in,
                              void* d_out, int out_size, void* d_ws, size_t ws_size,
                              hipStream_t stream) {
  const float* x   = (const float*)d_in[0];
  const float* adj = (const float*)d_in[1];
  const float* Ww  = (const float*)d_in[2];
  const float* Wb  = (const float*)d_in[3];
  const float* A   = (const float*)d_in[4];
  const float* gw  = (const float*)d_in[5];
  const float* gb  = (const float*)d_in[6];
  float* out = (float*)d_out;
  char* ws = (char*)d_ws;

  unsigned short* cat = (unsigned short*)(ws + CAT_OFF);
  unsigned short* vt  = (unsigned short*)(ws + VT_OFF);
  unsigned short* pun = (unsigned short*)(ws + PUN_OFF);
  float* s  = (float*)(ws + S_OFF);
  float* Wt = (float*)(ws + WT_OFF);

  hipMemsetAsync(s, 0, (size_t)B_ * N_ * sizeof(float), stream);
  k_wt<<<1, 256, 0, stream>>>(Ww, Wt);
  k1<<<(B_ * N_) / 8, 256, 0, stream>>>(x, Wt, Wb, A, cat);
  k2<<<dim3(16, 16, B_), 256, 0, stream>>>(cat, adj, pun, s);
  k1v<<<dim3(N_ / 64, B_), 256, 0, stream>>>(cat, s, vt);
  k3<<<dim3(N_ / 32, B_), 256, 0, stream>>>(pun, vt, x, gw, gb, out);
}

// Round 9
// 309.014 us; speedup vs baseline: 1.1319x; 1.1319x over previous
//
#include <hip/hip_runtime.h>

// GAT_gate: B=8, N=2048, D=128
// out = c*x + (1-c)*relu(att@h), att = colsoftmax(mask(hA h^T + h hA^T))*adj
// e small (|e|<~6) -> exp without max-subtraction (clamp 60).
// cat[n][0:128]=hA[n], cat[n][128:256]=h[n]; e[i,j] = cat[i] . catsw[j].
// R9 = R4 base (310us, passing) + two changes:
//  (1) k_bits2: adj -> 1-bit mask, fat blocks (32 elems/thread, no ballot);
//      k2 masks from 4B broadcast words instead of 64KB adj tiles/block.
//      Boolean-identical to adj>0 (zero numeric risk).
//  (2) k1 -> MFMA version (R6's, stride-136-aligned, re-audited).
// k3 = R4's LDS-staged version verbatim (K-split k3' of R5-R7 was the bug;
// R8 bisect proved it). k2 keeps R4's LDS cat staging (R8: no-LDS regressed).

#define B_ 8
#define N_ 2048
#define D_ 128

typedef __attribute__((ext_vector_type(8))) short short8;
typedef __attribute__((ext_vector_type(4))) float f32x4;

#define GLL(gp, lp) __builtin_amdgcn_global_load_lds( \
    (__attribute__((address_space(1))) const unsigned int*)(gp), \
    (__attribute__((address_space(3))) unsigned int*)(lp), 16, 0, 0)

static __device__ __forceinline__ unsigned short f2bf(float f) {
  union { float f; unsigned int u; } v; v.f = f;
  unsigned int r = v.u + 0x7fffu + ((v.u >> 16) & 1u);
  return (unsigned short)(r >> 16);
}
static __device__ __forceinline__ float bf2f(unsigned short u) {
  union { unsigned int u; float f; } v; v.u = ((unsigned int)u) << 16;
  return v.f;
}

// ---- workspace layout (bytes) ----
#define CAT_OFF  ((size_t)0)         // bf16 cat [B][N][256]        8 MB
#define VT_OFF   ((size_t)8388608)   // bf16 V'^T [B][128][N]       4 MB
#define PUN_OFF  ((size_t)12582912)  // bf16 P_un [B][N][N]         67.1 MB
#define S_OFF    ((size_t)79691776)  // f32 colsum s [B][N]         64 KB
#define WB_OFF   ((size_t)79757312)  // bf16 W [128][128]           32 KB
#define AT_OFF   ((size_t)79790080)  // bf16 A^T [128][128]         32 KB
#define BITS_OFF ((size_t)79822848)  // adj bits [B][N][N/32] uints 4 MB

// ---------- prep: W -> bf16 (same layout), A -> bf16 transposed ----------
__global__ void k_cvt(const float* __restrict__ W, const float* __restrict__ A,
                      unsigned short* __restrict__ Wb1, unsigned short* __restrict__ Abt) {
  int t = threadIdx.x;
  for (int i = t; i < 128 * 128; i += 256) {
    Wb1[i] = f2bf(W[i]);
    Abt[(i & 127) * 128 + (i >> 7)] = f2bf(A[i]);
  }
}

// ---------- k_bits2: adj -> bitmask, 32 contiguous elems/thread ----------
__global__ __launch_bounds__(256) void k_bits2(const float* __restrict__ adj,
                                               unsigned int* __restrict__ bits) {
  size_t tid = (size_t)blockIdx.x * 256 + threadIdx.x;
  const float* p = adj + tid * 32;
  unsigned int m = 0;
#pragma unroll
  for (int i = 0; i < 8; i++) {
    f32x4 v = *(const f32x4*)(p + i * 4);
    m |= (v[0] > 0.f ? 1u : 0u) << (i * 4 + 0);
    m |= (v[1] > 0.f ? 1u : 0u) << (i * 4 + 1);
    m |= (v[2] > 0.f ? 1u : 0u) << (i * 4 + 2);
    m |= (v[3] > 0.f ? 1u : 0u) << (i * 4 + 3);
  }
  bits[tid] = m;
}

// ---------- k1: h = x@W^T + b, hA = h@A via MFMA; write cat bf16 ----------
// grid 256 blocks; 4 waves; wave w owns rows blockIdx.x*64 + w*16 .. +16.
__global__ __launch_bounds__(256) void k1(const float* __restrict__ x,
                                          const unsigned short* __restrict__ Wb1,
                                          const float* __restrict__ Wbias,
                                          const unsigned short* __restrict__ Abt,
                                          unsigned short* __restrict__ cat) {
  __shared__ unsigned short hsm[4][16][136];   // 272 B rows, 16B-aligned
  __shared__ unsigned short hasm[4][16][136];
  const int t = threadIdx.x, w = t >> 6, lane = t & 63;
  const int q = lane >> 4, l15 = lane & 15;
  const size_t r0 = (size_t)blockIdx.x * 64 + w * 16;

  f32x4 acc[8];
#pragma unroll
  for (int dg = 0; dg < 8; dg++) acc[dg] = (f32x4){0.f, 0.f, 0.f, 0.f};
  // GEMM1: h = x @ W^T  (B[k=f][col=d] = W[d][f], contiguous in f)
#pragma unroll
  for (int k = 0; k < 4; k++) {
    const float* xp = x + (r0 + l15) * 128 + k * 32 + q * 8;
    f32x4 xa = *(const f32x4*)xp;
    f32x4 xb = *(const f32x4*)(xp + 4);
    short8 af;
#pragma unroll
    for (int e = 0; e < 4; e++) { af[e] = (short)f2bf(xa[e]); af[4 + e] = (short)f2bf(xb[e]); }
#pragma unroll
    for (int dg = 0; dg < 8; dg++) {
      short8 bf = *(const short8*)(Wb1 + (dg * 16 + l15) * 128 + k * 32 + q * 8);
      acc[dg] = __builtin_amdgcn_mfma_f32_16x16x32_bf16(af, bf, acc[dg], 0, 0, 0);
    }
  }
#pragma unroll
  for (int dg = 0; dg < 8; dg++) {
    float bias = Wbias[dg * 16 + l15];
#pragma unroll
    for (int r = 0; r < 4; r++)
      hsm[w][q * 4 + r][dg * 16 + l15] = f2bf(acc[dg][r] + bias);
  }
  __syncthreads();
  // GEMM2: hA = h @ A  (B[k=d][col=e] = A[d][e] = Abt[e][d], contiguous in d)
  f32x4 acc2[8];
#pragma unroll
  for (int dg = 0; dg < 8; dg++) acc2[dg] = (f32x4){0.f, 0.f, 0.f, 0.f};
#pragma unroll
  for (int k = 0; k < 4; k++) {
    short8 af = *(short8*)&hsm[w][l15][k * 32 + q * 8];
#pragma unroll
    for (int dg = 0; dg < 8; dg++) {
      short8 bf = *(const short8*)(Abt + (dg * 16 + l15) * 128 + k * 32 + q * 8);
      acc2[dg] = __builtin_amdgcn_mfma_f32_16x16x32_bf16(af, bf, acc2[dg], 0, 0, 0);
    }
  }
#pragma unroll
  for (int dg = 0; dg < 8; dg++)
#pragma unroll
    for (int r = 0; r < 4; r++)
      hasm[w][q * 4 + r][dg * 16 + l15] = f2bf(acc2[dg][r]);
  __syncthreads();
  // store cat: cols 0..127 = hA, cols 128..255 = h
#pragma unroll
  for (int it = 0; it < 8; it++) {
    int idx = it * 64 + lane;
    int row = idx >> 5, c = idx & 31;
    short8 v = (c < 16) ? *(short8*)&hasm[w][row][c * 8]
                        : *(short8*)&hsm[w][row][(c - 16) * 8];
    *(short8*)(cat + ((r0 + row) << 8) + c * 8) = v;
  }
}

// ---------- k2: E once; s[k] += mask*exp(E); P_un packed-pair bf16 ----------
// grid (N/128, 16, B); 4 waves; wave w owns k-cols [kbase+w*32, +32),
// lane pair cols kc+2*l15, kc+2*l15+1. LDS-staged cat tile (R4-proven),
// mask from bits words (4B broadcast per (jsub,r)).
__global__ __launch_bounds__(256, 3) void k2(const unsigned short* __restrict__ cat,
                                             const unsigned int* __restrict__ bits,
                                             unsigned short* __restrict__ pun,
                                             float* __restrict__ s_out) {
  __shared__ unsigned short cj[64 * 256];  // 32 KB, XOR-swizzled chunks
  const int t = threadIdx.x, w = t >> 6, lane = t & 63;
  const int q = lane >> 4, l15 = lane & 15;
  const int b = blockIdx.z;
  const int kbase = blockIdx.x * 128;
  const int j0b = blockIdx.y * 128;
  const size_t bN = (size_t)b * N_;
  const unsigned short* catp = cat + (bN << 8);
  const int kc = kbase + w * 32;
  const int kw = kc >> 5;  // bits word index within a row
  short8 brg[2][8];  // catsw_k fragments for cols kc+2*l15+p (swap +16 mod 32)
#pragma unroll
  for (int p = 0; p < 2; p++) {
    int krow = kc + 2 * l15 + p;
#pragma unroll
    for (int m = 0; m < 8; m++)
      brg[p][m] = *(const short8*)(catp + (((size_t)krow) << 8) +
                                   ((((m * 4 + q) + 16) & 31) * 8));
  }
  float acc0 = 0.f, acc1 = 0.f;
  for (int jt = 0; jt < 2; jt++) {
    const int j0 = j0b + jt * 64;
#pragma unroll
    for (int it = 0; it < 8; it++) {
      int sI = it * 256 + t;
      int row = sI >> 5, c = sI & 31;
      GLL(catp + (((size_t)(j0 + row)) << 8) + (c ^ (row & 7)) * 8,
          (char*)cj + sI * 16);
    }
    __syncthreads();
#pragma unroll
    for (int jsub = 0; jsub < 4; jsub++) {
      const int row = jsub * 16 + l15;
      short8 afr[8];
#pragma unroll
      for (int m = 0; m < 8; m++)
        afr[m] = *(short8*)(cj + row * 256 + (((m * 4 + q) ^ (l15 & 7)) * 8));
      f32x4 e0 = {0.f, 0.f, 0.f, 0.f}, e1 = {0.f, 0.f, 0.f, 0.f};
#pragma unroll
      for (int m = 0; m < 8; m++) {
        e0 = __builtin_amdgcn_mfma_f32_16x16x32_bf16(afr[m], brg[0][m], e0, 0, 0, 0);
        e1 = __builtin_amdgcn_mfma_f32_16x16x32_bf16(afr[m], brg[1][m], e1, 0, 0, 0);
      }
#pragma unroll
      for (int r = 0; r < 4; r++) {
        int jrow = j0 + jsub * 16 + q * 4 + r;
        unsigned int mb = bits[(bN + jrow) * 64 + kw];
        float x0 = ((mb >> (2 * l15)) & 1u) ? __expf(fminf(e0[r], 60.f)) : 0.f;
        float x1 = ((mb >> (2 * l15 + 1)) & 1u) ? __expf(fminf(e1[r], 60.f)) : 0.f;
        acc0 += x0; acc1 += x1;
        unsigned int pk = (unsigned int)f2bf(x0) | ((unsigned int)f2bf(x1) << 16);
        *(unsigned int*)(pun + ((bN + jrow) << 11) + kc + 2 * l15) = pk;
      }
    }
    __syncthreads();
  }
  acc0 += __shfl_xor(acc0, 16, 64); acc0 += __shfl_xor(acc0, 32, 64);
  acc1 += __shfl_xor(acc1, 16, 64); acc1 += __shfl_xor(acc1, 32, 64);
  if (lane < 16) {
    atomicAdd(&s_out[bN + kc + 2 * lane], acc0);
    atomicAdd(&s_out[bN + kc + 2 * lane + 1], acc1);
  }
}

// ---------- k1v: vt[b][d][j] = bf16(h[b][j][d] / s[j]) (R4-proven) ----------
__global__ __launch_bounds__(256) void k1v(const unsigned short* __restrict__ cat,
                                           const float* __restrict__ s,
                                           unsigned short* __restrict__ vt) {
  __shared__ unsigned short tile[64][136];
  __shared__ float rsv[64];
  const int t = threadIdx.x;
  const int b = blockIdx.y;
  const int nbase = blockIdx.x * 64;
  if (t < 64) rsv[t] = 1.f / s[(size_t)b * N_ + nbase + t];
#pragma unroll
  for (int k = 0; k < 4; k++) {
    int sI = t + 256 * k;
    int row = sI >> 4, part = sI & 15;
    *(short8*)&tile[row][part * 8] =
        *(const short8*)(cat + (((size_t)(b * N_ + nbase + row)) << 8) + 128 + part * 8);
  }
  __syncthreads();
#pragma unroll
  for (int k = 0; k < 4; k++) {
    int sI = t + 256 * k;
    int dd = sI >> 3, part = sI & 7;
    unsigned short tmp[8];
#pragma unroll
    for (int j = 0; j < 8; j++) {
      int jj = part * 8 + j;
      tmp[j] = f2bf(bf2f(tile[jj][dd]) * rsv[jj]);
    }
    *(short8*)(vt + (((size_t)(b * 128 + dd)) << 11) + nbase + part * 8) = *(short8*)tmp;
  }
}

// ---------- k3: h' = P_un @ V'; out = c*x + (1-c)*relu(h') (R4-proven) ----------
// grid (N/32, B); 4 waves; wave w owns d-group [w*32, w*32+32); j-tile 128.
__global__ __launch_bounds__(256) void k3(const unsigned short* __restrict__ pun,
                                          const unsigned short* __restrict__ vt,
                                          const float* __restrict__ x,
                                          const float* __restrict__ gw,
                                          const float* __restrict__ gb,
                                          float* __restrict__ out) {
  __shared__ char smem[40960];
  // [0,8192): A-tile P_un 32 x 128j   [8192,40960): B-tile vt 128d x 128j
  const int t = threadIdx.x, w = t >> 6, lane = t & 63;
  const int q = lane >> 4, l15 = lane & 15;
  const int b = blockIdx.y, i0 = blockIdx.x * 32;
  const size_t bN = (size_t)b * N_;
  unsigned short* pa = (unsigned short*)smem;
  unsigned short* vb = (unsigned short*)(smem + 8192);

  f32x4 acc[2][2];
#pragma unroll
  for (int ih = 0; ih < 2; ih++)
#pragma unroll
    for (int dh = 0; dh < 2; dh++) acc[ih][dh] = (f32x4){0.f, 0.f, 0.f, 0.f};

  for (int jt = 0; jt < N_ / 128; jt++) {
    const int j0 = jt * 128;
#pragma unroll
    for (int it = 0; it < 10; it++) {
      int sI = it * 256 + t;
      const unsigned short* g;
      if (sI < 512) {
        int row = sI >> 4, c = sI & 15;
        g = pun + (((size_t)(bN + i0 + row)) << 11) + j0 + ((c ^ (row & 7)) * 8);
      } else {
        int s2 = sI - 512;
        int dd = s2 >> 4, c = s2 & 15;
        g = vt + (((size_t)(b * 128 + dd)) << 11) + j0 + ((c ^ (dd & 7)) * 8);
      }
      GLL(g, smem + sI * 16);
    }
    __syncthreads();
#pragma unroll
    for (int ks = 0; ks < 4; ks++) {
      short8 af[2], bf[2];
#pragma unroll
      for (int ih = 0; ih < 2; ih++) {
        int m = ih * 16 + l15;
        af[ih] = *(short8*)(pa + m * 128 + (((ks * 4 + q) ^ (m & 7)) * 8));
      }
#pragma unroll
      for (int dh = 0; dh < 2; dh++) {
        int d = w * 32 + dh * 16 + l15;
        bf[dh] = *(short8*)(vb + d * 128 + (((ks * 4 + q) ^ (d & 7)) * 8));
      }
      acc[0][0] = __builtin_amdgcn_mfma_f32_16x16x32_bf16(af[0], bf[0], acc[0][0], 0, 0, 0);
      acc[0][1] = __builtin_amdgcn_mfma_f32_16x16x32_bf16(af[0], bf[1], acc[0][1], 0, 0, 0);
      acc[1][0] = __builtin_amdgcn_mfma_f32_16x16x32_bf16(af[1], bf[0], acc[1][0], 0, 0, 0);
      acc[1][1] = __builtin_amdgcn_mfma_f32_16x16x32_bf16(af[1], bf[1], acc[1][1], 0, 0, 0);
    }
    __syncthreads();
  }
  // epilogue: relu -> LDS f32, gate, sigmoid, blend, store
  float* hs = (float*)smem;            // 32 x 132 f32 = 16896 B
  float* co = (float*)(smem + 16896);  // 32 f32
#pragma unroll
  for (int ih = 0; ih < 2; ih++)
#pragma unroll
    for (int dh = 0; dh < 2; dh++)
#pragma unroll
      for (int r = 0; r < 4; r++) {
        int row = ih * 16 + q * 4 + r;
        int d = w * 32 + dh * 16 + l15;
        hs[row * 132 + d] = fmaxf(acc[ih][dh][r], 0.f);
      }
  __syncthreads();
  {
    int grow = t >> 3, sub = t & 7;
    const float* xr = x + (((size_t)(bN + i0 + grow)) << 7);
    float z = 0.f;
#pragma unroll
    for (int k = 0; k < 16; k++) {
      int dd = sub + 8 * k;
      z += gw[dd] * xr[dd] + gw[128 + dd] * hs[grow * 132 + dd];
    }
    z += __shfl_xor(z, 1, 64);
    z += __shfl_xor(z, 2, 64);
    z += __shfl_xor(z, 4, 64);
    if (sub == 0) co[grow] = 1.f / (1.f + __expf(-(z + gb[0])));
  }
  __syncthreads();
#pragma unroll
  for (int kk = 0; kk < 4; kk++) {
    int id = kk * 256 + t;
    int row = id >> 5, c4 = id & 31;
    size_t g = (((size_t)(bN + i0 + row)) << 7) + c4 * 4;
    f32x4 xv = *(const f32x4*)(x + g);
    f32x4 hv = *(const f32x4*)(hs + row * 132 + c4 * 4);
    float cf = co[row];
    f32x4 o;
#pragma unroll
    for (int e = 0; e < 4; e++) o[e] = cf * xv[e] + (1.f - cf) * hv[e];
    *(f32x4*)(out + g) = o;
  }
}

extern "C" void kernel_launch(void* const* d_in, const int* in_sizes, int n_in,
                              void* d_out, int out_size, void* d_ws, size_t ws_size,
                              hipStream_t stream) {
  const float* x   = (const float*)d_in[0];
  const float* adj = (const float*)d_in[1];
  const float* Ww  = (const float*)d_in[2];
  const float* Wb  = (const float*)d_in[3];
  const float* A   = (const float*)d_in[4];
  const float* gw  = (const float*)d_in[5];
  const float* gb  = (const float*)d_in[6];
  float* out = (float*)d_out;
  char* ws = (char*)d_ws;

  unsigned short* cat = (unsigned short*)(ws + CAT_OFF);
  unsigned short* vt  = (unsigned short*)(ws + VT_OFF);
  unsigned short* pun = (unsigned short*)(ws + PUN_OFF);
  float* s  = (float*)(ws + S_OFF);
  unsigned short* Wb1 = (unsigned short*)(ws + WB_OFF);
  unsigned short* Abt = (unsigned short*)(ws + AT_OFF);
  unsigned int* bits  = (unsigned int*)(ws + BITS_OFF);

  hipMemsetAsync(s, 0, (size_t)B_ * N_ * sizeof(float), stream);
  k_cvt<<<1, 256, 0, stream>>>(Ww, A, Wb1, Abt);
  k_bits2<<<(B_ * N_ * N_) / (256 * 32), 256, 0, stream>>>(adj, bits);
  k1<<<(B_ * N_) / 64, 256, 0, stream>>>(x, Wb1, Wb, Abt, cat);
  k2<<<dim3(N_ / 128, 16, B_), 256, 0, stream>>>(cat, bits, pun, s);
  k1v<<<dim3(N_ / 64, B_), 256, 0, stream>>>(cat, s, vt);
  k3<<<dim3(N_ / 32, B_), 256, 0, stream>>>(pun, vt, x, gw, gb, out);
}